// Round 9
// baseline (1769.743 us; speedup 1.0000x reference)
//
#include <hip/hip_runtime.h>

#define HW_ (256 * 256)

#define CE_ASC(arr, i, l)                  \
  {                                        \
    const float _a = arr[i], _b = arr[l];  \
    arr[i] = fminf(_a, _b);                \
    arr[l] = fmaxf(_a, _b);                \
  }
#define CE_DESC(arr, i, l)                 \
  {                                        \
    const float _a = arr[i], _b = arr[l];  \
    arr[i] = fmaxf(_a, _b);                \
    arr[l] = fminf(_a, _b);                \
  }

// Thread = (query row, key-half): 32 keys each. Wave = 32 rows x 2 key-halves.
// 2 waves per (window,head) unit; block = 256 threads = 2 units.
// Partner lane (lane^32) holds the other 32 keys of the same row.
// ALL register arrays statically indexed (rule #20); all-scalar FP (r3-proven
// codegen — no ext-vector temporaries in unrolled contract-off regions).
__global__ __launch_bounds__(256, 4)
void slice_attn_kernel(const float* __restrict__ Q,
                       const float* __restrict__ K,
                       const float* __restrict__ V,
                       const float* __restrict__ RT,
                       float* __restrict__ O) {
  // [unit][quad][kt][4]: b128 staging writes at the wave64 floor; score/PV
  // reads are 2-address broadcasts (conflict-free).
  __shared__ __align__(16) float k_lds[2][1024];
  __shared__ __align__(16) float v_lds[2][1024];
  __shared__ float bias_lds[225];  // rel-pos column for this head

  const int tid  = threadIdx.x;
  const int wave = tid >> 6;
  const int lane = tid & 63;
  const int bid  = blockIdx.x;

  const int w2       = wave >> 1;   // unit within block
  const int waveHalf = wave & 1;    // row group (and staging role: K vs V)
  const int keyHalf  = lane >> 5;   // key group within row
  const int row      = waveHalf * 32 + (lane & 31);

  // unit decode, wm innermost for L2 locality (h uniform across the block)
  const int unit = bid * 2 + w2;
  const int wm = unit & 31;
  const int wn = (unit >> 5) & 31;
  const int h  = (unit >> 10) & 7;
  const int b  = unit >> 13;

  if (tid < 225) bias_lds[tid] = RT[tid * 8 + h];

  const int base = (b * 128 + h * 16) * HW_;

  // ---- stage K (waveHalf 0) / V (waveHalf 1) for unit w2: lane -> key token
  {
    const int kh = lane >> 3, kw = lane & 7;
    const int yk = wn * 8 + kh;
    const int xk = (wm * 8 + kw - 4) & 255;  // roll right by 4 (wraps at wm==0)
    const float* sp = (waveHalf == 0 ? K : V) + base + yk * 256 + xk;
    float* dl = (waveHalf == 0 ? k_lds[w2] : v_lds[w2]);
    #pragma unroll
    for (int q4 = 0; q4 < 4; ++q4) {
      float4 vvv;
      vvv.x = sp[(q4 * 4 + 0) * HW_];
      vvv.y = sp[(q4 * 4 + 1) * HW_];
      vvv.z = sp[(q4 * 4 + 2) * HW_];
      vvv.w = sp[(q4 * 4 + 3) * HW_];
      *reinterpret_cast<float4*>(dl + q4 * 256 + lane * 4) = vvv;
    }
  }

  // ---- q for this row (pair lanes load same addrs: cache-served)
  const int sh = row >> 3, sw = row & 7;
  const int y = wn * 8 + sh, x = wm * 8 + sw;
  const float* qp = Q + base + y * 256 + x;
  float qr[16];
  #pragma unroll
  for (int i = 0; i < 16; ++i) qr[i] = qp[i * HW_] * 0.25f;  // *SCALE, pow2 exact
  __syncthreads();

  const float* kl = k_lds[w2];
  const float* vl = v_lds[w2];

  // ---- PASS 1: 32 scores (np-einsum-bit-exact tree: 4-lane SSE accumulator,
  //      NO fma, lane_j = ((p_j+p_{j+4})+p_{j+8})+p_{j+12}, (L0+L1)+(L2+L3)),
  //      streaming top-16: sort16 each 16-chunk + merge (r6/r8-HW-verified).
  float s[32];
  float A[16];
  {
    #pragma clang fp contract(off)
    #pragma unroll
    for (int ch = 0; ch < 2; ++ch) {
      float c[16];
      #pragma unroll
      for (int kk = 0; kk < 16; ++kk) {
        const int kt = keyHalf * 32 + ch * 16 + kk;
        const float4 k0 = *reinterpret_cast<const float4*>(kl + 0 * 256 + kt * 4);
        const float4 k1 = *reinterpret_cast<const float4*>(kl + 1 * 256 + kt * 4);
        const float4 k2 = *reinterpret_cast<const float4*>(kl + 2 * 256 + kt * 4);
        const float4 k3 = *reinterpret_cast<const float4*>(kl + 3 * 256 + kt * 4);
        const float p0  = qr[0]  * k0.x;
        const float p1  = qr[1]  * k0.y;
        const float p2  = qr[2]  * k0.z;
        const float p3  = qr[3]  * k0.w;
        const float p4  = qr[4]  * k1.x;
        const float p5  = qr[5]  * k1.y;
        const float p6  = qr[6]  * k1.z;
        const float p7  = qr[7]  * k1.w;
        const float p8  = qr[8]  * k2.x;
        const float p9  = qr[9]  * k2.y;
        const float p10 = qr[10] * k2.z;
        const float p11 = qr[11] * k2.w;
        const float p12 = qr[12] * k3.x;
        const float p13 = qr[13] * k3.y;
        const float p14 = qr[14] * k3.z;
        const float p15 = qr[15] * k3.w;
        const float L0 = ((p0 + p4) + p8)  + p12;
        const float L1 = ((p1 + p5) + p9)  + p13;
        const float L2 = ((p2 + p6) + p10) + p14;
        const float L3 = ((p3 + p7) + p11) + p15;
        const float val = (L0 + L1) + (L2 + L3);
        c[kk] = val;
        s[ch * 16 + kk] = val;
      }
      // bitonic sort16 ascending (80 CE)
      #pragma unroll
      for (int k = 2; k <= 16; k <<= 1) {
        #pragma unroll
        for (int j = k >> 1; j > 0; j >>= 1) {
          #pragma unroll
          for (int i = 0; i < 16; ++i) {
            const int l = i ^ j;
            if (l > i) {
              if ((i & k) == 0) { CE_ASC(c, i, l) } else { CE_DESC(c, i, l) }
            }
          }
        }
      }
      if (ch == 0) {
        #pragma unroll
        for (int i = 0; i < 16; ++i) A[i] = c[i];
      } else {
        // top-16 of (A asc) U (c asc): half-cleaner vs reversed c -> bitonic,
        // then ascending bitonic merge.
        float hm[16];
        #pragma unroll
        for (int i = 0; i < 16; ++i) hm[i] = fmaxf(A[i], c[15 - i]);
        #pragma unroll
        for (int j = 8; j > 0; j >>= 1) {
          #pragma unroll
          for (int i = 0; i < 16; ++i) {
            const int l = i ^ j;
            if (l > i) CE_ASC(hm, i, l)
          }
        }
        #pragma unroll
        for (int i = 0; i < 16; ++i) A[i] = hm[i];
      }
    }
  }

  // ---- cross-lane merge with partner: both lanes get the global top-16 asc
  {
    float Ao[16];
    #pragma unroll
    for (int i = 0; i < 16; ++i) Ao[i] = __shfl_xor(A[i], 32);
    float hm[16];
    #pragma unroll
    for (int i = 0; i < 16; ++i) hm[i] = fmaxf(A[i], Ao[15 - i]);
    #pragma unroll
    for (int j = 8; j > 0; j >>= 1) {
      #pragma unroll
      for (int i = 0; i < 16; ++i) {
        const int l = i ^ j;
        if (l > i) CE_ASC(hm, i, l)
      }
    }
    #pragma unroll
    for (int i = 0; i < 16; ++i) A[i] = hm[i];
  }

  const float thr = A[0];   // 16th largest (exact member of the score set)
  const float m   = A[15];  // pre-bias max (bias |.|<=~0.1 -> safe shift)
  int cgt = 0;              // strictly-greater count (all >thr are in top-16)
  #pragma unroll
  for (int i = 1; i < 16; ++i) cgt += (A[i] > thr) ? 1 : 0;

  // global index-ordered tie quota: half 1 starts after half 0's ties
  int eq_own = 0;
  #pragma unroll
  for (int j = 0; j < 32; ++j) eq_own += (s[j] == thr) ? 1 : 0;
  const int eq_other = __shfl_xor(eq_own, 32);
  int cnt = cgt + (keyHalf ? eq_other : 0);

  // ---- PASS 2: selection + bias + exp + denom + scalar-fma PV (own 32 keys)
  const int vbase = sh * 15 + sw;  // ridx = vbase + (112 - kh*15 - kw)
  const float* bp = &bias_lds[vbase];
  const bool edge = (wm == 0);

  float acc[16];
  #pragma unroll
  for (int j = 0; j < 16; ++j) acc[j] = 0.0f;
  float d0 = 0.0f, d1 = 0.0f;
  #pragma unroll
  for (int j = 0; j < 32; ++j) {
    const int ig = keyHalf * 32 + j;   // global key index
    const float sv = s[j];
    const bool eq = (sv == thr);
    bool take = (sv > thr) || (eq && (cnt < 16));
    cnt += eq ? 1 : 0;
    if (edge && (j & 7) < 4) take = false;  // post-softmax column mask
    const float bv = bp[112 - (ig >> 3) * 15 - (ig & 7)];
    const float p  = __expf(sv + bv - m);
    if (j & 1) d1 += p; else d0 += p;        // partial denominator
    const float w = take ? p : 0.0f;
    const float4 vq0 = *reinterpret_cast<const float4*>(vl + 0 * 256 + ig * 4);
    const float4 vq1 = *reinterpret_cast<const float4*>(vl + 1 * 256 + ig * 4);
    const float4 vq2 = *reinterpret_cast<const float4*>(vl + 2 * 256 + ig * 4);
    const float4 vq3 = *reinterpret_cast<const float4*>(vl + 3 * 256 + ig * 4);
    acc[0]  += w * vq0.x; acc[1]  += w * vq0.y; acc[2]  += w * vq0.z; acc[3]  += w * vq0.w;
    acc[4]  += w * vq1.x; acc[5]  += w * vq1.y; acc[6]  += w * vq1.z; acc[7]  += w * vq1.w;
    acc[8]  += w * vq2.x; acc[9]  += w * vq2.y; acc[10] += w * vq2.z; acc[11] += w * vq2.w;
    acc[12] += w * vq3.x; acc[13] += w * vq3.y; acc[14] += w * vq3.z; acc[15] += w * vq3.w;
  }

  // total denominator across the pair (convergent shfl)
  float d = d0 + d1;
  d += __shfl_xor(d, 32);
  const float inv = 1.0f / d;

  // ---- cross-lane PV reduce, ALL STATIC indices, convergent shfls:
  //      channel j total and channel 8+j total computed by both lanes;
  //      each lane stores its half (address depends on keyHalf — memory, ok).
  float* op = O + base + y * 256 + x + (keyHalf * 8) * HW_;
  #pragma unroll
  for (int j = 0; j < 8; ++j) {
    const float sum0 = acc[j]     + __shfl_xor(acc[j], 32);      // channel j
    const float sum1 = acc[8 + j] + __shfl_xor(acc[8 + j], 32);  // channel 8+j
    const float mine = keyHalf ? sum1 : sum0;                    // scalar select
    op[j * HW_] = mine * inv;
  }
}

extern "C" void kernel_launch(void* const* d_in, const int* in_sizes, int n_in,
                              void* d_out, int out_size, void* d_ws, size_t ws_size,
                              hipStream_t stream) {
  const float* Q  = (const float*)d_in[0];
  const float* K  = (const float*)d_in[1];
  const float* V  = (const float*)d_in[2];
  const float* RT = (const float*)d_in[3];
  float* O = (float*)d_out;
  dim3 grid(8192), block(256);
  hipLaunchKernelGGL(slice_attn_kernel, grid, block, 0, stream, Q, K, V, RT, O);
}

// Round 10
// 1714.444 us; speedup vs baseline: 1.0323x; 1.0323x over previous
//
#include <hip/hip_runtime.h>

#define HW_ (256 * 256)

#define CE_ASC(arr, i, l)                  \
  {                                        \
    const float _a = arr[i], _b = arr[l];  \
    arr[i] = fminf(_a, _b);                \
    arr[l] = fmaxf(_a, _b);                \
  }
#define CE_DESC(arr, i, l)                 \
  {                                        \
    const float _a = arr[i], _b = arr[l];  \
    arr[i] = fmaxf(_a, _b);                \
    arr[l] = fminf(_a, _b);                \
  }

// Thread = (query row, key-half): 32 keys each. Wave = 32 rows x 2 key-halves.
// 2 waves per (window,head) unit; block = 256 threads = 2 units.
// Partner lane (lane^32) holds the other 32 keys of the same row.
// Scores live in PADDED LDS (tid*33+j -> 2 lanes/bank, conflict-free), so the
// register live set in the unrolled sort region is only ~80 regs (r3-r9
// lesson: persistent reg arrays + unrolled sort networks = wholesale spill).
__global__ __launch_bounds__(256, 3)
void slice_attn_kernel(const float* __restrict__ Q,
                       const float* __restrict__ K,
                       const float* __restrict__ V,
                       const float* __restrict__ RT,
                       float* __restrict__ O) {
  __shared__ __align__(16) float k_lds[2][1024];
  __shared__ __align__(16) float v_lds[2][1024];
  __shared__ float bias_lds[225];       // rel-pos column for this head
  __shared__ float s_lds[256 * 33];     // per-thread 32 scores, +1 padded

  const int tid  = threadIdx.x;
  const int wave = tid >> 6;
  const int lane = tid & 63;
  const int bid  = blockIdx.x;

  const int w2       = wave >> 1;   // unit within block
  const int waveHalf = wave & 1;    // row group (and staging role: K vs V)
  const int keyHalf  = lane >> 5;   // key group within row
  const int row      = waveHalf * 32 + (lane & 31);

  // unit decode, wm innermost for L2 locality (h uniform across the block)
  const int unit = bid * 2 + w2;
  const int wm = unit & 31;
  const int wn = (unit >> 5) & 31;
  const int h  = (unit >> 10) & 7;
  const int b  = unit >> 13;

  if (tid < 225) bias_lds[tid] = RT[tid * 8 + h];

  const int base = (b * 128 + h * 16) * HW_;

  // ---- stage K (waveHalf 0) / V (waveHalf 1) for unit w2: lane -> key token
  {
    const int kh = lane >> 3, kw = lane & 7;
    const int yk = wn * 8 + kh;
    const int xk = (wm * 8 + kw - 4) & 255;  // roll right by 4 (wraps at wm==0)
    const float* sp = (waveHalf == 0 ? K : V) + base + yk * 256 + xk;
    float* dl = (waveHalf == 0 ? k_lds[w2] : v_lds[w2]);
    #pragma unroll
    for (int q4 = 0; q4 < 4; ++q4) {
      float4 vvv;
      vvv.x = sp[(q4 * 4 + 0) * HW_];
      vvv.y = sp[(q4 * 4 + 1) * HW_];
      vvv.z = sp[(q4 * 4 + 2) * HW_];
      vvv.w = sp[(q4 * 4 + 3) * HW_];
      *reinterpret_cast<float4*>(dl + q4 * 256 + lane * 4) = vvv;
    }
  }

  // ---- q for this row (pair lanes load same addrs: cache-served)
  const int sh = row >> 3, sw = row & 7;
  const int y = wn * 8 + sh, x = wm * 8 + sw;
  const float* qp = Q + base + y * 256 + x;
  float qr[16];
  #pragma unroll
  for (int i = 0; i < 16; ++i) qr[i] = qp[i * HW_] * 0.25f;  // *SCALE, pow2 exact
  __syncthreads();

  const float* kl = k_lds[w2];
  const float* vl = v_lds[w2];
  float* sl = s_lds + tid * 33;   // private score slot, bank = (tid+j)%32

  // ---- PASS 1: 32 scores (np-einsum-bit-exact tree: 4-lane SSE accumulator,
  //      NO fma, lane_j = ((p_j+p_{j+4})+p_{j+8})+p_{j+12}, (L0+L1)+(L2+L3));
  //      stash to LDS; streaming top-16 via sort16 + merge (r6/r8/r9-verified).
  float A[16];
  {
    #pragma clang fp contract(off)
    #pragma unroll
    for (int ch = 0; ch < 2; ++ch) {
      float c[16];
      #pragma unroll
      for (int kk = 0; kk < 16; ++kk) {
        const int kt = keyHalf * 32 + ch * 16 + kk;
        const float4 k0 = *reinterpret_cast<const float4*>(kl + 0 * 256 + kt * 4);
        const float4 k1 = *reinterpret_cast<const float4*>(kl + 1 * 256 + kt * 4);
        const float4 k2 = *reinterpret_cast<const float4*>(kl + 2 * 256 + kt * 4);
        const float4 k3 = *reinterpret_cast<const float4*>(kl + 3 * 256 + kt * 4);
        const float p0  = qr[0]  * k0.x;
        const float p1  = qr[1]  * k0.y;
        const float p2  = qr[2]  * k0.z;
        const float p3  = qr[3]  * k0.w;
        const float p4  = qr[4]  * k1.x;
        const float p5  = qr[5]  * k1.y;
        const float p6  = qr[6]  * k1.z;
        const float p7  = qr[7]  * k1.w;
        const float p8  = qr[8]  * k2.x;
        const float p9  = qr[9]  * k2.y;
        const float p10 = qr[10] * k2.z;
        const float p11 = qr[11] * k2.w;
        const float p12 = qr[12] * k3.x;
        const float p13 = qr[13] * k3.y;
        const float p14 = qr[14] * k3.z;
        const float p15 = qr[15] * k3.w;
        const float L0 = ((p0 + p4) + p8)  + p12;
        const float L1 = ((p1 + p5) + p9)  + p13;
        const float L2 = ((p2 + p6) + p10) + p14;
        const float L3 = ((p3 + p7) + p11) + p15;
        const float val = (L0 + L1) + (L2 + L3);
        c[kk] = val;
        sl[ch * 16 + kk] = val;
      }
      // bitonic sort16 ascending (80 CE)
      #pragma unroll
      for (int k = 2; k <= 16; k <<= 1) {
        #pragma unroll
        for (int j = k >> 1; j > 0; j >>= 1) {
          #pragma unroll
          for (int i = 0; i < 16; ++i) {
            const int l = i ^ j;
            if (l > i) {
              if ((i & k) == 0) { CE_ASC(c, i, l) } else { CE_DESC(c, i, l) }
            }
          }
        }
      }
      if (ch == 0) {
        #pragma unroll
        for (int i = 0; i < 16; ++i) A[i] = c[i];
      } else {
        // top-16 of (A asc) U (c asc): half-cleaner vs reversed c -> bitonic,
        // then ascending bitonic merge.
        float hm[16];
        #pragma unroll
        for (int i = 0; i < 16; ++i) hm[i] = fmaxf(A[i], c[15 - i]);
        #pragma unroll
        for (int j = 8; j > 0; j >>= 1) {
          #pragma unroll
          for (int i = 0; i < 16; ++i) {
            const int l = i ^ j;
            if (l > i) CE_ASC(hm, i, l)
          }
        }
        #pragma unroll
        for (int i = 0; i < 16; ++i) A[i] = hm[i];
      }
    }
  }

  // ---- cross-lane merge with partner: both lanes get the global top-16 asc
  {
    float Ao[16];
    #pragma unroll
    for (int i = 0; i < 16; ++i) Ao[i] = __shfl_xor(A[i], 32);
    float hm[16];
    #pragma unroll
    for (int i = 0; i < 16; ++i) hm[i] = fmaxf(A[i], Ao[15 - i]);
    #pragma unroll
    for (int j = 8; j > 0; j >>= 1) {
      #pragma unroll
      for (int i = 0; i < 16; ++i) {
        const int l = i ^ j;
        if (l > i) CE_ASC(hm, i, l)
      }
    }
    #pragma unroll
    for (int i = 0; i < 16; ++i) A[i] = hm[i];
  }

  const float thr = A[0];   // 16th largest (exact member of the score set)
  const float m   = A[15];  // pre-bias max (bias |.|<=~0.1 -> safe shift)
  int cgt = 0;              // strictly-greater count (all >thr are in top-16)
  #pragma unroll
  for (int i = 1; i < 16; ++i) cgt += (A[i] > thr) ? 1 : 0;

  // global index-ordered tie quota: half 1 starts after half 0's ties
  int eq_own = 0;
  #pragma unroll
  for (int j = 0; j < 32; ++j) eq_own += (sl[j] == thr) ? 1 : 0;
  const int eq_other = __shfl_xor(eq_own, 32);
  int cnt = cgt + (keyHalf ? eq_other : 0);

  // ---- PASS 2: selection + bias + exp + denom + scalar-fma PV (own 32 keys)
  const int vbase = sh * 15 + sw;  // ridx = vbase + (112 - kh*15 - kw)
  const float* bp = &bias_lds[vbase];
  const bool edge = (wm == 0);

  float acc[16];
  #pragma unroll
  for (int j = 0; j < 16; ++j) acc[j] = 0.0f;
  float d0 = 0.0f, d1 = 0.0f;
  #pragma unroll
  for (int j = 0; j < 32; ++j) {
    const int ig = keyHalf * 32 + j;   // global key index
    const float sv = sl[j];
    const bool eq = (sv == thr);
    bool take = (sv > thr) || (eq && (cnt < 16));
    cnt += eq ? 1 : 0;
    if (edge && (j & 7) < 4) take = false;  // post-softmax column mask
    const float bv = bp[112 - (ig >> 3) * 15 - (ig & 7)];
    const float p  = __expf(sv + bv - m);
    if (j & 1) d1 += p; else d0 += p;        // partial denominator
    const float w = take ? p : 0.0f;
    const float4 vq0 = *reinterpret_cast<const float4*>(vl + 0 * 256 + ig * 4);
    const float4 vq1 = *reinterpret_cast<const float4*>(vl + 1 * 256 + ig * 4);
    const float4 vq2 = *reinterpret_cast<const float4*>(vl + 2 * 256 + ig * 4);
    const float4 vq3 = *reinterpret_cast<const float4*>(vl + 3 * 256 + ig * 4);
    acc[0]  += w * vq0.x; acc[1]  += w * vq0.y; acc[2]  += w * vq0.z; acc[3]  += w * vq0.w;
    acc[4]  += w * vq1.x; acc[5]  += w * vq1.y; acc[6]  += w * vq1.z; acc[7]  += w * vq1.w;
    acc[8]  += w * vq2.x; acc[9]  += w * vq2.y; acc[10] += w * vq2.z; acc[11] += w * vq2.w;
    acc[12] += w * vq3.x; acc[13] += w * vq3.y; acc[14] += w * vq3.z; acc[15] += w * vq3.w;
  }

  // total denominator across the pair (convergent shfl)
  float d = d0 + d1;
  d += __shfl_xor(d, 32);
  const float inv = 1.0f / d;

  // ---- cross-lane PV reduce, ALL STATIC indices, convergent shfls:
  //      channel j total and channel 8+j total computed by both lanes;
  //      each lane stores its half (address depends on keyHalf — memory, ok).
  float* op = O + base + y * 256 + x + (keyHalf * 8) * HW_;
  #pragma unroll
  for (int j = 0; j < 8; ++j) {
    const float sum0 = acc[j]     + __shfl_xor(acc[j], 32);      // channel j
    const float sum1 = acc[8 + j] + __shfl_xor(acc[8 + j], 32);  // channel 8+j
    const float mine = keyHalf ? sum1 : sum0;                    // scalar select
    op[j * HW_] = mine * inv;
  }
}

extern "C" void kernel_launch(void* const* d_in, const int* in_sizes, int n_in,
                              void* d_out, int out_size, void* d_ws, size_t ws_size,
                              hipStream_t stream) {
  const float* Q  = (const float*)d_in[0];
  const float* K  = (const float*)d_in[1];
  const float* V  = (const float*)d_in[2];
  const float* RT = (const float*)d_in[3];
  float* O = (float*)d_out;
  dim3 grid(8192), block(256);
  hipLaunchKernelGGL(slice_attn_kernel, grid, block, 0, stream, Q, K, V, RT, O);
}

// Round 11
// 1710.808 us; speedup vs baseline: 1.0344x; 1.0021x over previous
//
#include <hip/hip_runtime.h>

#define HW_ (256 * 256)

#define CE_ASC(arr, i, l)                  \
  {                                        \
    const float _a = arr[i], _b = arr[l];  \
    arr[i] = fminf(_a, _b);                \
    arr[l] = fmaxf(_a, _b);                \
  }
#define CE_DESC(arr, i, l)                 \
  {                                        \
    const float _a = arr[i], _b = arr[l];  \
    arr[i] = fmaxf(_a, _b);                \
    arr[l] = fminf(_a, _b);                \
  }

// Thread = (query row, key-half): 32 keys each. Wave = 32 rows x 2 key-halves.
// 2 waves per (window,head) unit; block = 256 threads = 2 units.
// Partner lane (lane^32) holds the other 32 keys of the same row.
//
// Anti-spill structure (r3-r10 lesson): three register-disjoint regions,
// separated by LDS round-trips so the scheduler cannot merge them:
//   A) scores -> LDS (contract-off ONLY here, like all clean builds r2-r4)
//   B) one sort16 codegen instance (#pragma unroll 1) + merges
//   C) selection + softmax + PV (r3-proven shape)
__global__ __launch_bounds__(256, 3)
void slice_attn_kernel(const float* __restrict__ Q,
                       const float* __restrict__ K,
                       const float* __restrict__ V,
                       const float* __restrict__ RT,
                       float* __restrict__ O) {
  __shared__ __align__(16) float k_lds[2][1024];
  __shared__ __align__(16) float v_lds[2][1024];
  __shared__ float bias_lds[225];       // rel-pos column for this head
  __shared__ float s_lds[256 * 33];     // per-thread 32 scores, stride 33:
                                        // bank=(tid+j)%32 -> 2 lanes/bank, free

  const int tid  = threadIdx.x;
  const int wave = tid >> 6;
  const int lane = tid & 63;
  const int bid  = blockIdx.x;

  const int w2       = wave >> 1;   // unit within block
  const int waveHalf = wave & 1;    // row group (and staging role: K vs V)
  const int keyHalf  = lane >> 5;   // key group within row
  const int row      = waveHalf * 32 + (lane & 31);

  // unit decode, wm innermost for L2 locality (h uniform across the block)
  const int unit = bid * 2 + w2;
  const int wm = unit & 31;
  const int wn = (unit >> 5) & 31;
  const int h  = (unit >> 10) & 7;
  const int b  = unit >> 13;

  if (tid < 225) bias_lds[tid] = RT[tid * 8 + h];

  const int base = (b * 128 + h * 16) * HW_;

  // ---- stage K (waveHalf 0) / V (waveHalf 1) for unit w2: lane -> key token
  {
    const int kh = lane >> 3, kw = lane & 7;
    const int yk = wn * 8 + kh;
    const int xk = (wm * 8 + kw - 4) & 255;  // roll right by 4 (wraps at wm==0)
    const float* sp = (waveHalf == 0 ? K : V) + base + yk * 256 + xk;
    float* dl = (waveHalf == 0 ? k_lds[w2] : v_lds[w2]);
    #pragma unroll
    for (int q4 = 0; q4 < 4; ++q4) {
      float4 vvv;
      vvv.x = sp[(q4 * 4 + 0) * HW_];
      vvv.y = sp[(q4 * 4 + 1) * HW_];
      vvv.z = sp[(q4 * 4 + 2) * HW_];
      vvv.w = sp[(q4 * 4 + 3) * HW_];
      *reinterpret_cast<float4*>(dl + q4 * 256 + lane * 4) = vvv;
    }
  }

  // ---- q for this row (pair lanes load same addrs: cache-served)
  const int sh = row >> 3, sw = row & 7;
  const int y = wn * 8 + sh, x = wm * 8 + sw;
  const float* qp = Q + base + y * 256 + x;
  float qr[16];
  #pragma unroll
  for (int i = 0; i < 16; ++i) qr[i] = qp[i * HW_] * 0.25f;  // *SCALE, pow2 exact
  __syncthreads();

  const float* kl = k_lds[w2];
  const float* vl = v_lds[w2];
  float* sl = s_lds + tid * 33;   // private score slot

  // ==== REGION A: own 32 scores -> LDS. np-einsum-bit-exact tree
  //      (4-lane SSE accumulator, NO fma, lane_j=((p_j+p_{j+4})+p_{j+8})+p_{j+12},
  //       horizontal (L0+L1)+(L2+L3)). contract(off) scoped HERE ONLY.
  {
    #pragma clang fp contract(off)
    #pragma unroll
    for (int j = 0; j < 32; ++j) {
      const int kt = keyHalf * 32 + j;
      const float4 k0 = *reinterpret_cast<const float4*>(kl + 0 * 256 + kt * 4);
      const float4 k1 = *reinterpret_cast<const float4*>(kl + 1 * 256 + kt * 4);
      const float4 k2 = *reinterpret_cast<const float4*>(kl + 2 * 256 + kt * 4);
      const float4 k3 = *reinterpret_cast<const float4*>(kl + 3 * 256 + kt * 4);
      const float p0  = qr[0]  * k0.x;
      const float p1  = qr[1]  * k0.y;
      const float p2  = qr[2]  * k0.z;
      const float p3  = qr[3]  * k0.w;
      const float p4  = qr[4]  * k1.x;
      const float p5  = qr[5]  * k1.y;
      const float p6  = qr[6]  * k1.z;
      const float p7  = qr[7]  * k1.w;
      const float p8  = qr[8]  * k2.x;
      const float p9  = qr[9]  * k2.y;
      const float p10 = qr[10] * k2.z;
      const float p11 = qr[11] * k2.w;
      const float p12 = qr[12] * k3.x;
      const float p13 = qr[13] * k3.y;
      const float p14 = qr[14] * k3.z;
      const float p15 = qr[15] * k3.w;
      const float L0 = ((p0 + p4) + p8)  + p12;
      const float L1 = ((p1 + p5) + p9)  + p13;
      const float L2 = ((p2 + p6) + p10) + p14;
      const float L3 = ((p3 + p7) + p11) + p15;
      sl[j] = (L0 + L1) + (L2 + L3);
    }
  }

  // ==== REGION B: streaming top-16 (ONE sort16 instance via unroll 1).
  float A[16];
  #pragma unroll 1
  for (int ch = 0; ch < 2; ++ch) {
    float c[16];
    #pragma unroll
    for (int i = 0; i < 16; ++i) c[i] = sl[ch * 16 + i];
    // bitonic sort16 ascending (80 CE, static indices)
    #pragma unroll
    for (int k = 2; k <= 16; k <<= 1) {
      #pragma unroll
      for (int j = k >> 1; j > 0; j >>= 1) {
        #pragma unroll
        for (int i = 0; i < 16; ++i) {
          const int l = i ^ j;
          if (l > i) {
            if ((i & k) == 0) { CE_ASC(c, i, l) } else { CE_DESC(c, i, l) }
          }
        }
      }
    }
    if (ch == 0) {
      #pragma unroll
      for (int i = 0; i < 16; ++i) A[i] = c[i];
    } else {
      // top-16 of (A asc) U (c asc): half-cleaner vs reversed c -> bitonic,
      // then ascending bitonic merge (r6/r8/r9/r10 HW-verified).
      float hm[16];
      #pragma unroll
      for (int i = 0; i < 16; ++i) hm[i] = fmaxf(A[i], c[15 - i]);
      #pragma unroll
      for (int j = 8; j > 0; j >>= 1) {
        #pragma unroll
        for (int i = 0; i < 16; ++i) {
          const int l = i ^ j;
          if (l > i) CE_ASC(hm, i, l)
        }
      }
      #pragma unroll
      for (int i = 0; i < 16; ++i) A[i] = hm[i];
    }
  }

  // cross-lane merge with partner: both lanes get the global top-16 asc
  {
    float Ao[16];
    #pragma unroll
    for (int i = 0; i < 16; ++i) Ao[i] = __shfl_xor(A[i], 32);
    float hm[16];
    #pragma unroll
    for (int i = 0; i < 16; ++i) hm[i] = fmaxf(A[i], Ao[15 - i]);
    #pragma unroll
    for (int j = 8; j > 0; j >>= 1) {
      #pragma unroll
      for (int i = 0; i < 16; ++i) {
        const int l = i ^ j;
        if (l > i) CE_ASC(hm, i, l)
      }
    }
    #pragma unroll
    for (int i = 0; i < 16; ++i) A[i] = hm[i];
  }

  const float thr = A[0];   // 16th largest (exact member of the score set)
  const float m   = A[15];  // pre-bias max (bias |.|<=~0.1 -> safe shift)
  int cgt = 0;              // strictly-greater count (all >thr are in top-16)
  #pragma unroll
  for (int i = 1; i < 16; ++i) cgt += (A[i] > thr) ? 1 : 0;

  // global index-ordered tie quota: half 1 starts after half 0's ties
  int eq_own = 0;
  #pragma unroll
  for (int j = 0; j < 32; ++j) eq_own += (sl[j] == thr) ? 1 : 0;
  const int eq_other = __shfl_xor(eq_own, 32);
  int cnt = cgt + (keyHalf ? eq_other : 0);

  // ==== REGION C: selection + bias + exp + denom + scalar-fma PV (own 32 keys)
  const int vbase = sh * 15 + sw;  // ridx = vbase + (112 - kh*15 - kw)
  const float* bp = &bias_lds[vbase];
  const bool edge = (wm == 0);

  float acc[16];
  #pragma unroll
  for (int j = 0; j < 16; ++j) acc[j] = 0.0f;
  float d0 = 0.0f, d1 = 0.0f;
  #pragma unroll
  for (int j = 0; j < 32; ++j) {
    const int ig = keyHalf * 32 + j;   // global key index
    const float sv = sl[j];
    const bool eq = (sv == thr);
    bool take = (sv > thr) || (eq && (cnt < 16));
    cnt += eq ? 1 : 0;
    if (edge && (j & 7) < 4) take = false;  // post-softmax column mask
    const float bv = bp[112 - (ig >> 3) * 15 - (ig & 7)];
    const float p  = __expf(sv + bv - m);
    if (j & 1) d1 += p; else d0 += p;        // partial denominator
    const float w = take ? p : 0.0f;
    const float4 vq0 = *reinterpret_cast<const float4*>(vl + 0 * 256 + ig * 4);
    const float4 vq1 = *reinterpret_cast<const float4*>(vl + 1 * 256 + ig * 4);
    const float4 vq2 = *reinterpret_cast<const float4*>(vl + 2 * 256 + ig * 4);
    const float4 vq3 = *reinterpret_cast<const float4*>(vl + 3 * 256 + ig * 4);
    acc[0]  += w * vq0.x; acc[1]  += w * vq0.y; acc[2]  += w * vq0.z; acc[3]  += w * vq0.w;
    acc[4]  += w * vq1.x; acc[5]  += w * vq1.y; acc[6]  += w * vq1.z; acc[7]  += w * vq1.w;
    acc[8]  += w * vq2.x; acc[9]  += w * vq2.y; acc[10] += w * vq2.z; acc[11] += w * vq2.w;
    acc[12] += w * vq3.x; acc[13] += w * vq3.y; acc[14] += w * vq3.z; acc[15] += w * vq3.w;
  }

  // total denominator across the pair (convergent shfl)
  float d = d0 + d1;
  d += __shfl_xor(d, 32);
  const float inv = 1.0f / d;

  // cross-lane PV reduce, ALL STATIC indices, convergent shfls; each lane
  // stores channels [keyHalf*8, keyHalf*8+8) (address depends on keyHalf only).
  float* op = O + base + y * 256 + x + (keyHalf * 8) * HW_;
  #pragma unroll
  for (int j = 0; j < 8; ++j) {
    const float sum0 = acc[j]     + __shfl_xor(acc[j], 32);      // channel j
    const float sum1 = acc[8 + j] + __shfl_xor(acc[8 + j], 32);  // channel 8+j
    const float mine = keyHalf ? sum1 : sum0;                    // scalar select
    op[j * HW_] = mine * inv;
  }
}

extern "C" void kernel_launch(void* const* d_in, const int* in_sizes, int n_in,
                              void* d_out, int out_size, void* d_ws, size_t ws_size,
                              hipStream_t stream) {
  const float* Q  = (const float*)d_in[0];
  const float* K  = (const float*)d_in[1];
  const float* V  = (const float*)d_in[2];
  const float* RT = (const float*)d_in[3];
  float* O = (float*)d_out;
  dim3 grid(8192), block(256);
  hipLaunchKernelGGL(slice_attn_kernel, grid, block, 0, stream, Q, K, V, RT, O);
}

// Round 12
// 303.975 us; speedup vs baseline: 5.8220x; 5.6281x over previous
//
#include <hip/hip_runtime.h>

#define HW_ (256 * 256)

// Thread = (query row, key-quarter): 16 keys each. Quartet lanes
// {r, r+16, r+32, r+48} of one wave cooperate on one row (shfl_xor 16/32).
// Block = 256 threads = ONE (window, head) unit. Grid = 16384.
// Code idioms copied from r3 (the only clean+fast build): ONE persistent
// score array + small tree temps + serial chains + unroll-1 outer loop.
// NO sort networks (every build containing them spilled: r5-r11).
__global__ __launch_bounds__(256, 4)
void slice_attn_kernel(const float* __restrict__ Q,
                       const float* __restrict__ K,
                       const float* __restrict__ V,
                       const float* __restrict__ RT,
                       float* __restrict__ O) {
  __shared__ __align__(16) float k_lds[1024];  // [ch4][key][4]
  __shared__ __align__(16) float v_lds[1024];
  __shared__ float bias_lds[225];              // rel-pos column for this head

  const int tid  = threadIdx.x;
  const int wave = tid >> 6;
  const int lane = tid & 63;
  const int r    = lane & 15;     // row-within-wave
  const int q    = lane >> 4;     // key quarter (0..3)
  const int row  = wave * 16 + r; // query token 0..63

  // unit decode, wm innermost for L2 locality
  const int unit = blockIdx.x;
  const int wm = unit & 31;
  const int wn = (unit >> 5) & 31;
  const int h  = (unit >> 10) & 7;
  const int b  = unit >> 13;

  if (tid < 225) bias_lds[tid] = RT[tid * 8 + h];

  const int base = (b * 128 + h * 16) * HW_;

  // ---- stage K and V: thread (key = tid&63, ch4 = tid>>6) loads 4 channels
  {
    const int key = tid & 63;
    const int c4g = tid >> 6;
    const int kh = key >> 3, kw = key & 7;
    const int yk = wn * 8 + kh;
    const int xk = (wm * 8 + kw - 4) & 255;  // roll right by 4 (wraps at wm==0)
    const float* kp = K + base + yk * 256 + xk;
    const float* vp = V + base + yk * 256 + xk;
    float4 kv, vv;
    kv.x = kp[(c4g * 4 + 0) * HW_];
    kv.y = kp[(c4g * 4 + 1) * HW_];
    kv.z = kp[(c4g * 4 + 2) * HW_];
    kv.w = kp[(c4g * 4 + 3) * HW_];
    vv.x = vp[(c4g * 4 + 0) * HW_];
    vv.y = vp[(c4g * 4 + 1) * HW_];
    vv.z = vp[(c4g * 4 + 2) * HW_];
    vv.w = vp[(c4g * 4 + 3) * HW_];
    *reinterpret_cast<float4*>(k_lds + c4g * 256 + key * 4) = kv;
    *reinterpret_cast<float4*>(v_lds + c4g * 256 + key * 4) = vv;
  }

  // ---- q for this row (quartet lanes share addresses: cache broadcast)
  const int sh = row >> 3, sw = row & 7;
  const int y = wn * 8 + sh, x = wm * 8 + sw;
  const float* qp = Q + base + y * 256 + x;
  float qr[16];
  #pragma unroll
  for (int i = 0; i < 16; ++i) qr[i] = qp[i * HW_] * 0.25f;  // *SCALE, pow2 exact
  __syncthreads();

  // ---- scores for own 16 keys: np-einsum-bit-exact tree (4-lane SSE
  //      accumulator, NO fma, lane_j=((p_j+p_{j+4})+p_{j+8})+p_{j+12},
  //      horizontal (L0+L1)+(L2+L3)); contract(off) scoped here only.
  float s[16];
  {
    #pragma clang fp contract(off)
    #pragma unroll
    for (int j = 0; j < 16; ++j) {
      const int kt = q * 16 + j;
      const float4 k0 = *reinterpret_cast<const float4*>(k_lds + 0 * 256 + kt * 4);
      const float4 k1 = *reinterpret_cast<const float4*>(k_lds + 1 * 256 + kt * 4);
      const float4 k2 = *reinterpret_cast<const float4*>(k_lds + 2 * 256 + kt * 4);
      const float4 k3 = *reinterpret_cast<const float4*>(k_lds + 3 * 256 + kt * 4);
      const float p0  = qr[0]  * k0.x;
      const float p1  = qr[1]  * k0.y;
      const float p2  = qr[2]  * k0.z;
      const float p3  = qr[3]  * k0.w;
      const float p4  = qr[4]  * k1.x;
      const float p5  = qr[5]  * k1.y;
      const float p6  = qr[6]  * k1.z;
      const float p7  = qr[7]  * k1.w;
      const float p8  = qr[8]  * k2.x;
      const float p9  = qr[9]  * k2.y;
      const float p10 = qr[10] * k2.z;
      const float p11 = qr[11] * k2.w;
      const float p12 = qr[12] * k3.x;
      const float p13 = qr[13] * k3.y;
      const float p14 = qr[14] * k3.z;
      const float p15 = qr[15] * k3.w;
      const float L0 = ((p0 + p4) + p8)  + p12;
      const float L1 = ((p1 + p5) + p9)  + p13;
      const float L2 = ((p2 + p6) + p10) + p14;
      const float L3 = ((p3 + p7) + p11) + p15;
      s[j] = (L0 + L1) + (L2 + L3);
    }
  }

  // ---- top-16 knockout, 16 rounds (r3 semantics, quartet-cooperative).
  //      Lowest-global-index copy of the round max is knocked to mv-1024.
  //      Selection ends up encoded as s[j] < -512. First-index arbitration
  //      via ballot: only the lowest quartet lane holding mv knocks.
  const unsigned long long bitp = 1ull << lane;
  // mask of quartet lanes strictly below mine (bits 16*q' + r, q' < q)
  const unsigned long long lmask =
      (q > 0 ? (1ull << r) : 0ull) |
      (q > 1 ? (1ull << (16 + r)) : 0ull) |
      (q > 2 ? (1ull << (32 + r)) : 0ull);
  (void)bitp;

  float m = 0.0f;  // round-0 global max (softmax shift)
  #pragma unroll 1
  for (int rr = 0; rr < 16; ++rr) {
    // own tree-max over 16 (15 fmax, r3's tmp-tree shape)
    float t8[8];
    #pragma unroll
    for (int i = 0; i < 8; ++i) t8[i] = fmaxf(s[i], s[i + 8]);
    #pragma unroll
    for (int wdt = 4; wdt >= 1; wdt >>= 1) {
      #pragma unroll
      for (int i = 0; i < wdt; ++i) t8[i] = fmaxf(t8[i], t8[i + wdt]);
    }
    const float own = t8[0];
    float mv = fmaxf(own, __shfl_xor(own, 16));
    mv = fmaxf(mv, __shfl_xor(mv, 32));
    if (rr == 0) m = mv;
    const bool has = (own == mv);
    const unsigned long long bal = __ballot(has);
    bool taken = (bal & lmask) != 0ull;  // a lower quartet lane owns the max
    const float kv2 = mv - 1024.0f;
    #pragma unroll
    for (int j = 0; j < 16; ++j) {
      const bool hit = (!taken) && (s[j] == mv);
      s[j] = hit ? kv2 : s[j];
      taken = taken || hit;
    }
  }

  // ---- fused: restore originals (±6e-5, r3-passed), bias + exp + denom + PV
  const int vbase = sh * 15 + sw;  // ridx = vbase + (112 - kh*15 - kw)
  const float* bp = &bias_lds[vbase];
  const bool edge = (wm == 0);

  float acc[16];
  #pragma unroll
  for (int j = 0; j < 16; ++j) acc[j] = 0.0f;
  float d0 = 0.0f, d1 = 0.0f;
  #pragma unroll
  for (int j = 0; j < 16; ++j) {
    const int ig = q * 16 + j;   // global key index
    const float sv = s[j];
    const bool sel = sv < -512.0f;
    const float orig = sel ? sv + 1024.0f : sv;
    const float bv = bp[112 - (ig >> 3) * 15 - (ig & 7)];
    const float p  = __expf(orig + bv - m);
    if (j & 1) d1 += p; else d0 += p;   // denominator over ALL keys
    float w = sel ? p : 0.0f;
    if (edge && (ig & 7) < 4) w = 0.0f; // post-softmax column mask
    const float4 vq0 = *reinterpret_cast<const float4*>(v_lds + 0 * 256 + ig * 4);
    const float4 vq1 = *reinterpret_cast<const float4*>(v_lds + 1 * 256 + ig * 4);
    const float4 vq2 = *reinterpret_cast<const float4*>(v_lds + 2 * 256 + ig * 4);
    const float4 vq3 = *reinterpret_cast<const float4*>(v_lds + 3 * 256 + ig * 4);
    acc[0]  += w * vq0.x; acc[1]  += w * vq0.y; acc[2]  += w * vq0.z; acc[3]  += w * vq0.w;
    acc[4]  += w * vq1.x; acc[5]  += w * vq1.y; acc[6]  += w * vq1.z; acc[7]  += w * vq1.w;
    acc[8]  += w * vq2.x; acc[9]  += w * vq2.y; acc[10] += w * vq2.z; acc[11] += w * vq2.w;
    acc[12] += w * vq3.x; acc[13] += w * vq3.y; acc[14] += w * vq3.z; acc[15] += w * vq3.w;
  }

  // quartet reduce: denominator and all 16 channels (convergent shfls)
  float d = d0 + d1;
  d += __shfl_xor(d, 16);
  d += __shfl_xor(d, 32);
  const float inv = 1.0f / d;
  #pragma unroll
  for (int j = 0; j < 16; ++j) {
    acc[j] += __shfl_xor(acc[j], 16);
    acc[j] += __shfl_xor(acc[j], 32);
  }

  // ---- store: lane q writes channels q*4..q*4+3, static-index select ladder
  float* op = O + base + y * 256 + x + (q * 4) * HW_;
  #pragma unroll
  for (int jj = 0; jj < 4; ++jj) {
    const float s01 = (q & 1) ? acc[4 + jj]  : acc[jj];
    const float s23 = (q & 1) ? acc[12 + jj] : acc[8 + jj];
    const float val = (q & 2) ? s23 : s01;
    op[jj * HW_] = val * inv;
  }
}

extern "C" void kernel_launch(void* const* d_in, const int* in_sizes, int n_in,
                              void* d_out, int out_size, void* d_ws, size_t ws_size,
                              hipStream_t stream) {
  const float* Q  = (const float*)d_in[0];
  const float* K  = (const float*)d_in[1];
  const float* V  = (const float*)d_in[2];
  const float* RT = (const float*)d_in[3];
  float* O = (float*)d_out;
  dim3 grid(16384), block(256);
  hipLaunchKernelGGL(slice_attn_kernel, grid, block, 0, stream, Q, K, V, RT, O);
}